// Round 6
// baseline (513.225 us; speedup 1.0000x reference)
//
#include <hip/hip_runtime.h>
#include <math.h>

#define B_           1024
#define S_           200
#define H_           128
#define VOCAB_       100000
#define PAD_ID_      99998
#define INTEREST_ID_ 99999
#define NTHREADS_    512   // 8 waves/block; 1024 blocks -> 4 blocks/CU

typedef float vfloat4 __attribute__((ext_vector_type(4)));

// One block per batch row, WAVE-SPECIALIZED:
//   waves 0-3 (tid 0..255):   zero-fill out[b,:] with NT 16B stores ONLY.
//   waves 4-7 (tid 256..511): score compute (loads ONLY, next-row prefetch).
// Rationale: vmcnt is a single IN-ORDER counter per wave shared by loads and
// stores. In the previous versions each wave issued ~49 fill stores before its
// score loads, so the first load's s_waitcnt had to drain the whole store
// stream -> write phase and read phase serialized (~140 us vs ~85 us roofline).
// Separate waves = separate vmcnt counters = true read/write overlap.
// Then: __syncthreads (drains fill stores), masked softmax over 200 scores,
// atomicAdd scatter into the row this block exclusively owns.
__global__ __launch_bounds__(NTHREADS_) void rd90220_fused_v6(
    const float* __restrict__ hs,
    const int*   __restrict__ ids,
    const float* __restrict__ w,
    const float* __restrict__ bp,
    float*       __restrict__ out)
{
    __shared__ float s_scores[S_];
    __shared__ float s_red[16];

    const int batch = blockIdx.x;
    const int tid   = threadIdx.x;
    const int wave  = tid >> 6;
    const int lane  = tid & 63;

    const float* hsb  = hs + (size_t)batch * (S_ * H_);
    float*       rowo = out + (size_t)batch * VOCAB_;

    if (wave < 4) {
        // ---- Fill waves: zero this block's output row (25000 x 16B = 400 KB).
        // Pure store stream; drains at HBM write BW while score waves read.
        vfloat4* rowo4 = (vfloat4*)rowo;
        const vfloat4 z = {0.f, 0.f, 0.f, 0.f};
        for (int i = tid; i < VOCAB_ / 4; i += 256)
            __builtin_nontemporal_store(z, rowo4 + i);
    } else {
        // ---- Score waves: pure load stream.
        // wave w in {0..3}; half-wave per row; lane hl covers h = hl*4..hl*4+3.
        const int w4   = wave - 4;
        const int half = lane >> 5;
        const int hl   = lane & 31;

        const vfloat4 key = ((const vfloat4*)hsb)[hl];
        const vfloat4 wv  = ((const vfloat4*)w)[hl];

        // rows: s = i*8 + w4*2 + half, i in [0,25) -> covers [0,200) exactly
        const int sbase = w4 * 2 + half;
        vfloat4 x = __builtin_nontemporal_load(
            ((const vfloat4*)(hsb + sbase * H_)) + hl);
        #pragma unroll
        for (int i = 0; i < 25; ++i) {
            const vfloat4 cur = x;
            if (i + 1 < 25) {
                const int sn = (i + 1) * 8 + sbase;   // prefetch next row
                x = __builtin_nontemporal_load(
                    ((const vfloat4*)(hsb + sn * H_)) + hl);
            }
            float acc = tanhf(cur.x + key.x) * wv.x
                      + tanhf(cur.y + key.y) * wv.y
                      + tanhf(cur.z + key.z) * wv.z
                      + tanhf(cur.w + key.w) * wv.w;
            #pragma unroll
            for (int off = 16; off; off >>= 1)        // xor <32 stays in-half
                acc += __shfl_xor(acc, off, 64);
            if (hl == 0) s_scores[i * 8 + sbase] = acc;
        }
    }

    // Token ids (loaded by fill-wave threads tid<200; needed only post-barrier)
    int   id    = 0;
    bool  valid = false;
    if (tid < S_) {
        id    = ids[batch * S_ + tid];
        valid = (id != PAD_ID_) && (id != INTEREST_ID_);
    }

    __syncthreads();   // scores in LDS; fill stores drained

    // ---- Masked softmax over 200 scores ----
    const float bias = bp[0];
    float sc = (tid < S_ && valid) ? (s_scores[tid] + bias) : -INFINITY;

    float m = sc;
    #pragma unroll
    for (int off = 32; off; off >>= 1)
        m = fmaxf(m, __shfl_down(m, off, 64));
    if (lane == 0) s_red[wave] = m;
    __syncthreads();
    m = fmaxf(fmaxf(fmaxf(s_red[0], s_red[1]), fmaxf(s_red[2], s_red[3])),
              fmaxf(fmaxf(s_red[4], s_red[5]), fmaxf(s_red[6], s_red[7])));

    const float e = (tid < S_ && valid) ? expf(sc - m) : 0.0f;
    float t = e;
    #pragma unroll
    for (int off = 32; off; off >>= 1)
        t += __shfl_down(t, off, 64);
    if (lane == 0) s_red[8 + wave] = t;
    __syncthreads();
    const float sum = (s_red[8]  + s_red[9])  + (s_red[10] + s_red[11])
                    + (s_red[12] + s_red[13]) + (s_red[14] + s_red[15]);

    // ---- Scatter (duplicate ids within a row possible -> atomicAdd) ----
    if (tid < S_ && valid) {
        atomicAdd(&rowo[id], e / sum);
    }
}

extern "C" void kernel_launch(void* const* d_in, const int* in_sizes, int n_in,
                              void* d_out, int out_size, void* d_ws, size_t ws_size,
                              hipStream_t stream) {
    const float* hs  = (const float*)d_in[0];
    const int*   ids = (const int*)d_in[1];
    const float* w   = (const float*)d_in[2];
    const float* bp  = (const float*)d_in[3];
    float*       out = (float*)d_out;

    rd90220_fused_v6<<<B_, NTHREADS_, 0, stream>>>(hs, ids, w, bp, out);
}

// Round 7
// 488.914 us; speedup vs baseline: 1.0497x; 1.0497x over previous
//
#include <hip/hip_runtime.h>
#include <math.h>

#define B_           1024
#define S_           200
#define H_           128
#define VOCAB_       100000
#define PAD_ID_      99998
#define INTEREST_ID_ 99999

typedef float vfloat4 __attribute__((ext_vector_type(4)));

// Two-dispatch design (R7):
//   1) hipMemsetAsync zeroes the 410 MB output at proven rocclr fill rate
//      (~6.2 TB/s = ~66 us; same engine as the harness's own poison fills).
//   2) This kernel does ONLY score+softmax+scatter: 1024 blocks x 256 thr
//      (8 blocks/CU = 16 waves/CU), half-wave per row, float4 loads with
//      next-row software prefetch, 5-step in-half xor-reduce, then a
//      256-thread masked softmax and <=200 atomicAdds into the row.
// Rationale: R1-R6 showed fill+compute in ONE kernel is ~140 us no matter
// the structure, while rocclr's fill alone is 66 us; R1's slow split was due
// to its latency-bound compute kernel (float2, no prefetch, 6-step reduce).
__global__ __launch_bounds__(256) void rd90220_score_scatter(
    const float* __restrict__ hs,
    const int*   __restrict__ ids,
    const float* __restrict__ w,
    const float* __restrict__ bp,
    float*       __restrict__ out)
{
    __shared__ float s_scores[S_];
    __shared__ float s_red[8];

    const int batch = blockIdx.x;
    const int tid   = threadIdx.x;
    const int wave  = tid >> 6;    // 0..3
    const int lane  = tid & 63;
    const int half  = lane >> 5;   // which of the wave's 2 rows
    const int hl    = lane & 31;   // lane within half: h = hl*4 .. hl*4+3

    const float* hsb  = hs + (size_t)batch * (S_ * H_);
    float*       rowo = out + (size_t)batch * VOCAB_;

    // Token id (single-use; issue early, consumed after the barrier).
    int   id    = 0;
    bool  valid = false;
    if (tid < S_) {
        id    = ids[batch * S_ + tid];
        valid = (id != PAD_ID_) && (id != INTEREST_ID_);
    }

    // Per-lane constants: key = hs[b,0,h..h+3], wv = w[h..h+3]
    const vfloat4 key = ((const vfloat4*)hsb)[hl];
    const vfloat4 wv  = ((const vfloat4*)w)[hl];

    // rows: s = i*8 + wave*2 + half, i in [0,25) -> covers [0,200) exactly
    const int sbase = wave * 2 + half;
    vfloat4 x = __builtin_nontemporal_load(
        ((const vfloat4*)(hsb + sbase * H_)) + hl);
    #pragma unroll
    for (int i = 0; i < 25; ++i) {
        const vfloat4 cur = x;
        if (i + 1 < 25) {                              // prefetch next row
            const int sn = (i + 1) * 8 + sbase;
            x = __builtin_nontemporal_load(
                ((const vfloat4*)(hsb + sn * H_)) + hl);
        }
        float acc = tanhf(cur.x + key.x) * wv.x
                  + tanhf(cur.y + key.y) * wv.y
                  + tanhf(cur.z + key.z) * wv.z
                  + tanhf(cur.w + key.w) * wv.w;
        #pragma unroll
        for (int off = 16; off; off >>= 1)             // xor <32 stays in-half
            acc += __shfl_xor(acc, off, 64);
        if (hl == 0) s_scores[i * 8 + sbase] = acc;
    }

    __syncthreads();

    // ---- Masked softmax over 200 scores (4 waves, 256 threads) ----
    const float bias = bp[0];
    float sc = (tid < S_ && valid) ? (s_scores[tid] + bias) : -INFINITY;

    float m = sc;
    #pragma unroll
    for (int off = 32; off; off >>= 1)
        m = fmaxf(m, __shfl_down(m, off, 64));
    if (lane == 0) s_red[wave] = m;
    __syncthreads();
    m = fmaxf(fmaxf(s_red[0], s_red[1]), fmaxf(s_red[2], s_red[3]));

    const float e = (tid < S_ && valid) ? expf(sc - m) : 0.0f;
    float t = e;
    #pragma unroll
    for (int off = 32; off; off >>= 1)
        t += __shfl_down(t, off, 64);
    if (lane == 0) s_red[4 + wave] = t;
    __syncthreads();
    const float sum = (s_red[4] + s_red[5]) + (s_red[6] + s_red[7]);

    // ---- Scatter (duplicate ids within a row possible -> atomicAdd) ----
    if (tid < S_ && valid) {
        atomicAdd(&rowo[id], e / sum);
    }
}

extern "C" void kernel_launch(void* const* d_in, const int* in_sizes, int n_in,
                              void* d_out, int out_size, void* d_ws, size_t ws_size,
                              hipStream_t stream) {
    const float* hs  = (const float*)d_in[0];
    const int*   ids = (const int*)d_in[1];
    const float* w   = (const float*)d_in[2];
    const float* bp  = (const float*)d_in[3];
    float*       out = (float*)d_out;

    // Zero the 409.6 MB output at rocclr fill rate (~6.2 TB/s, ~66 us).
    hipMemsetAsync(d_out, 0, (size_t)out_size * sizeof(float), stream);

    // Lean compute+scatter (~20-25 us): stream-ordered after the memset.
    rd90220_score_scatter<<<B_, 256, 0, stream>>>(hs, ids, w, bp, out);
}